// Round 17
// baseline (196.823 us; speedup 1.0000x reference)
//
#include <hip/hip_runtime.h>

#define ZC     256
#define KCODES 1024
#define MARGIN 4e-4f   // hi-only bf16 GEMM: gap-error sigma ~4e-5 -> 10 sigma
#define WIN    1e-4f   // screen->candidate window (bound ~3.2e-5, 3x headroom)
#define NPT    32768

typedef __attribute__((ext_vector_type(4))) float f32x4;
typedef __attribute__((ext_vector_type(8))) short s16x8;
typedef unsigned int u32t;
typedef u32t __attribute__((address_space(1))) as1_u32;
typedef u32t __attribute__((address_space(3))) as3_u32;

__device__ __forceinline__ void glds16(const void* g, void* l) {
    __builtin_amdgcn_global_load_lds((const as1_u32*)g, (as3_u32*)l, 16, 0, 0);
}
__device__ __forceinline__ unsigned short bf16_rn(float x) {
    union { float f; u32t u; } v; v.f = x;
    return (unsigned short)((v.u + 0x7FFFu + ((v.u >> 16) & 1u)) >> 16);
}

// ---------------------------------------------------------------------------
// prep_z (verified r12-r16): z -> A' bf16 [4 kblk][32768 pt][64 k], swizzled.
// ---------------------------------------------------------------------------
__global__ __launch_bounds__(256)
void vq_prep_z(const float* __restrict__ z, unsigned short* __restrict__ Ab)
{
    const int t = threadIdx.x, blk = blockIdx.x;
    const int pt = (blk >> 3) * 64 + (t & 63);
    const int c0 = (blk & 7) * 32 + (t >> 6) * 8;
    const int b = pt >> 10, hw = pt & 1023;
    const float* zp = z + (size_t)b * (ZC * 1024) + (size_t)c0 * 1024 + hw;

    unsigned short hi[8];
    #pragma unroll
    for (int j = 0; j < 8; ++j) hi[j] = bf16_rn(zp[(size_t)j * 1024]);
    uint4 ph;
    ph.x = (u32t)hi[0] | ((u32t)hi[1] << 16); ph.y = (u32t)hi[2] | ((u32t)hi[3] << 16);
    ph.z = (u32t)hi[4] | ((u32t)hi[5] << 16); ph.w = (u32t)hi[6] | ((u32t)hi[7] << 16);

    const size_t kb = (size_t)(c0 >> 6);
    const int sw = (c0 & 63) ^ ((pt & 7) << 3);
    *reinterpret_cast<uint4*>(Ab + kb * (32768ull * 64) + (size_t)pt * 64 + sw) = ph;
}

// ---------------------------------------------------------------------------
// prep_e (verified r12-r16): emb -> B' bf16 [4 kblk][1024 code][64], swizzled.
// ---------------------------------------------------------------------------
__global__ __launch_bounds__(256)
void vq_prep_e(const float* __restrict__ emb, unsigned short* __restrict__ Bb)
{
    const int t = threadIdx.x, blk = blockIdx.x;
    const int code = (blk >> 3) * 64 + (t & 63);
    const int c0 = (blk & 7) * 32 + (t >> 6) * 8;
    const float* ep = emb + (size_t)code * ZC + c0;

    unsigned short hi[8];
    #pragma unroll
    for (int j = 0; j < 8; ++j) hi[j] = bf16_rn(ep[j]);
    uint4 ph;
    ph.x = (u32t)hi[0] | ((u32t)hi[1] << 16); ph.y = (u32t)hi[2] | ((u32t)hi[3] << 16);
    ph.z = (u32t)hi[4] | ((u32t)hi[5] << 16); ph.w = (u32t)hi[6] | ((u32t)hi[7] << 16);

    const size_t kb = (size_t)(c0 >> 6);
    const int sw = (c0 & 63) ^ ((code & 7) << 3);
    *reinterpret_cast<uint4*>(Bb + kb * (1024ull * 64) + (size_t)code * 64 + sw) = ph;
}

// ---------------------------------------------------------------------------
// ens_np (verified r13-r16): np-pairwise-exact codebook norms; zeroes counter.
// ---------------------------------------------------------------------------
__global__ __launch_bounds__(256)
void vq_ens_np(const float* __restrict__ emb, float* __restrict__ ens_np,
               int* __restrict__ cnt)
{
    if (blockIdx.x == 0 && threadIdx.x == 0) *cnt = 0;
    const int t = threadIdx.x, g = t >> 3, r = t & 7;
    const int code = blockIdx.x * 32 + g;
    const float* er = emb + (size_t)code * ZC;

    float lo, hi;
    {
        const float a0 = er[r], a1 = er[128 + r];
        lo = __fmul_rn(a0, a0); hi = __fmul_rn(a1, a1);
    }
    #pragma unroll
    for (int i = 1; i < 16; ++i) {
        const int c = 8 * i + r;
        const float a0 = er[c], a1 = er[128 + c];
        lo = __fadd_rn(lo, __fmul_rn(a0, a0));
        hi = __fadd_rn(hi, __fmul_rn(a1, a1));
    }
    #pragma unroll
    for (int mk = 1; mk < 8; mk <<= 1) {
        lo = __fadd_rn(lo, __shfl_xor(lo, mk));
        hi = __fadd_rn(hi, __shfl_xor(hi, mk));
    }
    if (r == 0) ens_np[code] = __fadd_rn(lo, hi);
}

// ---------------------------------------------------------------------------
// GEMM+argmin: r12-r16 verified inner loop (K=256 hi-only, 4 waves, 24 KB
// LDS, 2-barrier k-step); grid 1024 = (512 pt-tiles) x (2 code-halves) ->
// 4 blocks/CU (r16 was grid-limited to 2). Per-half top-2 partials out;
// vq_merge (r11-verified) folds. bounds(256,2) — NOT 4 (r9/r10 spill).
// ---------------------------------------------------------------------------
__global__ __launch_bounds__(256, 2)
void vq_gemm_argmin(const unsigned short* __restrict__ Ab,
                    const unsigned short* __restrict__ Bb,
                    const float* __restrict__ ens_g,
                    float* __restrict__ partV1, float* __restrict__ partV2,
                    int* __restrict__ partI)
{
    __shared__ unsigned short As[64 * 64];
    __shared__ unsigned short Bs[128 * 64];

    const int t = threadIdx.x;
    const int lane = t & 63, wv = t >> 6;
    const int col = lane & 15, kg = lane >> 4;
    const int blk = blockIdx.x;
    const int pt0 = (blk >> 1) * 64;
    const int half = blk & 1;
    const int kx = (col & 7) << 3;

    int aoff[4][2], boff[2][2];
    #pragma unroll
    for (int m = 0; m < 4; ++m)
        #pragma unroll
        for (int s = 0; s < 2; ++s)
            aoff[m][s] = (m * 16 + col) * 64 + ((s * 32 + kg * 8) ^ kx);
    #pragma unroll
    for (int n = 0; n < 2; ++n)
        #pragma unroll
        for (int s = 0; s < 2; ++s)
            boff[n][s] = (wv * 32 + n * 16 + col) * 64 + ((s * 32 + kg * 8) ^ kx);

    f32x4 acc[4][2];
    #pragma unroll
    for (int m = 0; m < 4; ++m)
        #pragma unroll
        for (int n = 0; n < 2; ++n) acc[m][n] = (f32x4){0.f, 0.f, 0.f, 0.f};

    float v1[16], v2[16]; int id1[16];
    #pragma unroll
    for (int i = 0; i < 16; ++i) { v1[i] = 3.4e38f; v2[i] = 3.4e38f; id1[i] = 0; }

    for (int ci = 0; ci < 4; ++ci) {
        const int ct = half * 4 + ci;
        for (int ks = 0; ks < 4; ++ks) {
            const char* aS = (const char*)(Ab + (size_t)ks * 2097152ull + (size_t)pt0 * 64);
            const char* bS = (const char*)(Bb + (size_t)ks * 65536ull + (size_t)ct * 8192);

            __syncthreads();
            glds16(aS + t * 16,        (char*)As + t * 16);
            glds16(aS + 4096 + t * 16, (char*)As + 4096 + t * 16);
            #pragma unroll
            for (int q = 0; q < 4; ++q)
                glds16(bS + q * 4096 + t * 16, (char*)Bs + q * 4096 + t * 16);
            __syncthreads();

            s16x8 af[4][2], bf[2][2];
            #pragma unroll
            for (int m = 0; m < 4; ++m)
                #pragma unroll
                for (int s = 0; s < 2; ++s)
                    af[m][s] = *reinterpret_cast<const s16x8*>(As + aoff[m][s]);
            #pragma unroll
            for (int n = 0; n < 2; ++n)
                #pragma unroll
                for (int s = 0; s < 2; ++s)
                    bf[n][s] = *reinterpret_cast<const s16x8*>(Bs + boff[n][s]);
            #pragma unroll
            for (int m = 0; m < 4; ++m)
                #pragma unroll
                for (int n = 0; n < 2; ++n) {
                    acc[m][n] = __builtin_amdgcn_mfma_f32_16x16x32_bf16(af[m][0], bf[n][0], acc[m][n], 0, 0, 0);
                    acc[m][n] = __builtin_amdgcn_mfma_f32_16x16x32_bf16(af[m][1], bf[n][1], acc[m][n], 0, 0, 0);
                }

            if (ks == 3) {
                #pragma unroll
                for (int n = 0; n < 2; ++n) {
                    const int code = ct * 128 + wv * 32 + n * 16 + col;
                    const float en = ens_g[code];
                    #pragma unroll
                    for (int m = 0; m < 4; ++m)
                        #pragma unroll
                        for (int j = 0; j < 4; ++j) {
                            const float sc = fmaf(-2.f, acc[m][n][j], en);
                            const int sl = m * 4 + j;
                            if (sc < v1[sl]) { v2[sl] = v1[sl]; v1[sl] = sc; id1[sl] = code; }
                            else if (sc < v2[sl]) { v2[sl] = sc; }
                            acc[m][n][j] = 0.f;
                        }
                }
            }
        }
    }

    // in-wave 16-lane top-2 merge (verified rounds 5-16)
    float w1[16], w2[16]; int wid[16];
    #pragma unroll
    for (int sl = 0; sl < 16; ++sl) {
        float a1 = v1[sl]; int ai = id1[sl]; float a2 = v2[sl];
        #pragma unroll
        for (int mk = 1; mk < 16; mk <<= 1) {
            const float o1 = __shfl_xor(a1, mk);
            const int   oi = __shfl_xor(ai, mk);
            const float o2 = __shfl_xor(a2, mk);
            if (o1 < a1)      { a2 = fminf(a1, o2); a1 = o1; ai = oi; }
            else if (o1 > a1) { a2 = fminf(a2, o1); }
            else              { a2 = (oi != ai) ? a1 : fminf(a2, o2); ai = (oi < ai) ? oi : ai; }
        }
        w1[sl] = a1; w2[sl] = a2; wid[sl] = ai;
    }

    // cross-wave merge via LDS (verified rounds 5-16)
    __syncthreads();
    float* mv1 = reinterpret_cast<float*>(As);
    float* mv2 = mv1 + 256;
    int*   mid = reinterpret_cast<int*>(mv2 + 256);
    if (col == 0) {
        #pragma unroll
        for (int sl = 0; sl < 16; ++sl) {
            const int m = sl >> 2, j = sl & 3;
            const int p = m * 16 + kg * 4 + j;
            mv1[wv * 64 + p] = w1[sl];
            mv2[wv * 64 + p] = w2[sl];
            mid[wv * 64 + p] = wid[sl];
        }
    }
    __syncthreads();
    if (t < 64) {
        float a1 = mv1[t], a2 = mv2[t]; int ai = mid[t];
        #pragma unroll
        for (int w = 1; w < 4; ++w) {
            const float b1 = mv1[w * 64 + t], b2 = mv2[w * 64 + t];
            const int   bi = mid[w * 64 + t];
            if (b1 < a1)      { a2 = fminf(a1, b2); a1 = b1; ai = bi; }
            else if (b1 > a1) { a2 = fminf(a2, b1); }
            else              { a2 = a1; ai = (bi < ai) ? bi : ai; }
        }
        const int g = half * NPT + pt0 + t;
        partV1[g] = a1; partV2[g] = a2; partI[g] = ai;
    }
}

// ---------------------------------------------------------------------------
// merge (verified r11): fold the two code-half top-2s into flag-encoded
// out_idx. Half-0 codes < half-1 codes -> equal-value tie keeps min index.
// ---------------------------------------------------------------------------
__global__ __launch_bounds__(256)
void vq_merge(const float* __restrict__ partV1, const float* __restrict__ partV2,
              const int* __restrict__ partI, float* __restrict__ out_idx)
{
    const int n = blockIdx.x * 256 + threadIdx.x;
    const float a1 = partV1[n],       a2 = partV2[n];
    const int   ai = partI[n];
    const float b1 = partV1[NPT + n], b2 = partV2[NPT + n];
    const int   bi = partI[NPT + n];
    float v1f, v2f; int idf;
    if (b1 < a1)      { v1f = b1; idf = bi; v2f = fminf(a1, b2); }
    else if (b1 > a1) { v1f = a1; idf = ai; v2f = fminf(a2, b1); }
    else              { v1f = a1; idf = (bi < ai) ? bi : ai; v2f = a1; }
    out_idx[n] = ((v2f - v1f) <= MARGIN) ? (-1.0f - (float)idf) : (float)idf;
}

// ---------------------------------------------------------------------------
// compact: flagged points -> worklist.
// ---------------------------------------------------------------------------
__global__ __launch_bounds__(256)
void vq_compact(const float* __restrict__ idxf, int* __restrict__ cnt,
                int* __restrict__ list)
{
    const int n = blockIdx.x * 256 + threadIdx.x;
    if (idxf[n] < 0.f) { const int p = atomicAdd(cnt, 1); list[p] = n; }
}

// ---------------------------------------------------------------------------
// fixup6 (verified r16): reg-dbuf f32 screen + candidate collection +
// f64 np-exact adjudication. Unchanged.
// ---------------------------------------------------------------------------
__global__ __launch_bounds__(256, 1)
void vq_fixup6(const float* __restrict__ z, const float* __restrict__ emb,
               const float* __restrict__ ens_np, float* __restrict__ idxf,
               const int* __restrict__ cnt, const int* __restrict__ list)
{
    __shared__ float  zsb[4 * 264];
    __shared__ float  scr[4 * 1024];
    __shared__ float  znv[4];
    __shared__ float  smin[4];
    __shared__ int    pn[4];
    __shared__ float  redm[4];
    __shared__ int    candk[128];
    __shared__ int    candp[128];
    __shared__ int    ccnt;
    __shared__ double dred[4];
    __shared__ float  bestd_s[4];
    __shared__ int    bestk_s[4];

    const int t = threadIdx.x;
    const int g = t >> 3, r = t & 7;
    const int C = *cnt;
    const int base = blockIdx.x * 4;
    if (base >= C) return;
    const int npts = (C - base < 4) ? (C - base) : 4;

    if (t < 4) pn[t] = (base + t < C) ? list[base + t] : list[base];
    if (t == 0) ccnt = 0;
    __syncthreads();
    #pragma unroll
    for (int p = 0; p < 4; ++p) {
        const int n = pn[p];
        const int b = n >> 10, q = n & 1023;
        zsb[p * 264 + t] = z[(size_t)b * (ZC * 1024) + (size_t)t * 1024 + q];
    }
    __syncthreads();

    if (t < 32) {
        const float* zp = zsb + g * 264;
        float lo = __fmul_rn(zp[r], zp[r]);
        float hi = __fmul_rn(zp[128 + r], zp[128 + r]);
        #pragma unroll
        for (int i = 1; i < 16; ++i) {
            const int c = 8 * i + r;
            lo = __fadd_rn(lo, __fmul_rn(zp[c], zp[c]));
            hi = __fadd_rn(hi, __fmul_rn(zp[128 + c], zp[128 + c]));
        }
        #pragma unroll
        for (int mk = 1; mk < 8; mk <<= 1) {
            lo = __fadd_rn(lo, __shfl_xor(lo, mk));
            hi = __fadd_rn(hi, __shfl_xor(hi, mk));
        }
        if (r == 0) znv[g] = __fadd_rn(lo, hi);
    }

    const float* zb0 = zsb + 0 * 264 + r * 4;
    const float* zb1 = zsb + 1 * 264 + r * 4;
    const float* zb2 = zsb + 2 * 264 + r * 4;
    const float* zb3 = zsb + 3 * 264 + r * 4;

    float4 eA0, eA1, eA2, eA3, eA4, eA5, eA6, eA7;
    {
        const float* er = emb + (size_t)g * ZC + r * 4;
        eA0 = *reinterpret_cast<const float4*>(er);
        eA1 = *reinterpret_cast<const float4*>(er + 32);
        eA2 = *reinterpret_cast<const float4*>(er + 64);
        eA3 = *reinterpret_cast<const float4*>(er + 96);
        eA4 = *reinterpret_cast<const float4*>(er + 128);
        eA5 = *reinterpret_cast<const float4*>(er + 160);
        eA6 = *reinterpret_cast<const float4*>(er + 192);
        eA7 = *reinterpret_cast<const float4*>(er + 224);
    }

    for (int tile = 0; tile < 32; ++tile) {
        float4 eB0, eB1, eB2, eB3, eB4, eB5, eB6, eB7;
        if (tile < 31) {
            const float* er = emb + (size_t)(tile + 1) * 32 * ZC + (size_t)g * ZC + r * 4;
            eB0 = *reinterpret_cast<const float4*>(er);
            eB1 = *reinterpret_cast<const float4*>(er + 32);
            eB2 = *reinterpret_cast<const float4*>(er + 64);
            eB3 = *reinterpret_cast<const float4*>(er + 96);
            eB4 = *reinterpret_cast<const float4*>(er + 128);
            eB5 = *reinterpret_cast<const float4*>(er + 160);
            eB6 = *reinterpret_cast<const float4*>(er + 192);
            eB7 = *reinterpret_cast<const float4*>(er + 224);
        }

        float s0 = 0.f, s1 = 0.f, s2 = 0.f, s3 = 0.f;
        #define SCREEN_STEP(EV, OFF)                                           \
        {                                                                      \
            const float4 a0 = *reinterpret_cast<const float4*>(zb0 + (OFF));   \
            const float4 a1 = *reinterpret_cast<const float4*>(zb1 + (OFF));   \
            const float4 a2 = *reinterpret_cast<const float4*>(zb2 + (OFF));   \
            const float4 a3 = *reinterpret_cast<const float4*>(zb3 + (OFF));   \
            s0 = fmaf(EV.x, a0.x, s0); s0 = fmaf(EV.y, a0.y, s0);              \
            s0 = fmaf(EV.z, a0.z, s0); s0 = fmaf(EV.w, a0.w, s0);              \
            s1 = fmaf(EV.x, a1.x, s1); s1 = fmaf(EV.y, a1.y, s1);              \
            s1 = fmaf(EV.z, a1.z, s1); s1 = fmaf(EV.w, a1.w, s1);              \
            s2 = fmaf(EV.x, a2.x, s2); s2 = fmaf(EV.y, a2.y, s2);              \
            s2 = fmaf(EV.z, a2.z, s2); s2 = fmaf(EV.w, a2.w, s2);              \
            s3 = fmaf(EV.x, a3.x, s3); s3 = fmaf(EV.y, a3.y, s3);              \
            s3 = fmaf(EV.z, a3.z, s3); s3 = fmaf(EV.w, a3.w, s3);              \
        }
        SCREEN_STEP(eA0, 0)
        SCREEN_STEP(eA1, 32)
        SCREEN_STEP(eA2, 64)
        SCREEN_STEP(eA3, 96)
        SCREEN_STEP(eA4, 128)
        SCREEN_STEP(eA5, 160)
        SCREEN_STEP(eA6, 192)
        SCREEN_STEP(eA7, 224)
        #undef SCREEN_STEP

        #pragma unroll
        for (int mk = 1; mk < 8; mk <<= 1) {
            s0 += __shfl_xor(s0, mk);
            s1 += __shfl_xor(s1, mk);
            s2 += __shfl_xor(s2, mk);
            s3 += __shfl_xor(s3, mk);
        }
        if (r == 0) {
            const int code = tile * 32 + g;
            const float en = ens_np[code];
            scr[0 * 1024 + code] = fmaf(-2.f, s0, en);
            scr[1 * 1024 + code] = fmaf(-2.f, s1, en);
            scr[2 * 1024 + code] = fmaf(-2.f, s2, en);
            scr[3 * 1024 + code] = fmaf(-2.f, s3, en);
        }

        eA0 = eB0; eA1 = eB1; eA2 = eB2; eA3 = eB3;
        eA4 = eB4; eA5 = eB5; eA6 = eB6; eA7 = eB7;
    }
    __syncthreads();

    for (int p = 0; p < 4; ++p) {
        float m = fminf(fminf(scr[p * 1024 + t],       scr[p * 1024 + t + 256]),
                        fminf(scr[p * 1024 + t + 512], scr[p * 1024 + t + 768]));
        #pragma unroll
        for (int mk = 1; mk < 64; mk <<= 1) m = fminf(m, __shfl_xor(m, mk));
        if ((t & 63) == 0) redm[t >> 6] = m;
        __syncthreads();
        if (t == 0) smin[p] = fminf(fminf(redm[0], redm[1]), fminf(redm[2], redm[3]));
        __syncthreads();
    }

    for (int p = 0; p < 4; ++p) {
        #pragma unroll
        for (int rep = 0; rep < 4; ++rep) {
            const int code = rep * 256 + t;
            if (scr[p * 1024 + code] <= smin[p] + WIN) {
                const int pos = atomicAdd(&ccnt, 1);
                if (pos < 128) { candk[pos] = code; candp[pos] = p; }
            }
        }
    }
    __syncthreads();
    const int NC = (ccnt < 128) ? ccnt : 128;

    if (t < 4) { bestd_s[t] = 3.4e38f; bestk_s[t] = 0x7fffffff; }
    __syncthreads();
    for (int ci = 0; ci < NC; ++ci) {
        const int code = candk[ci], p = candp[ci];
        double dd = (double)emb[(size_t)code * ZC + t] * (double)zsb[p * 264 + t];
        #pragma unroll
        for (int mk = 1; mk < 64; mk <<= 1) dd = dd + __shfl_xor(dd, mk);
        if ((t & 63) == 0) dred[t >> 6] = dd;
        __syncthreads();
        if (t == 0) {
            const double tot = (dred[0] + dred[1]) + (dred[2] + dred[3]);
            const float t2f = (float)tot;
            const float d = __fsub_rn(__fadd_rn(znv[p], ens_np[code]),
                                      __fmul_rn(2.0f, t2f));
            if (d < bestd_s[p] || (d == bestd_s[p] && code < bestk_s[p])) {
                bestd_s[p] = d; bestk_s[p] = code;
            }
        }
        __syncthreads();
    }
    if (t < npts) idxf[pn[t]] = (float)bestk_s[t];
}

// ---------------------------------------------------------------------------
// outputs (verified round 2) — overwrites the scratch regions.
// ---------------------------------------------------------------------------
__global__ __launch_bounds__(256)
void vq_outputs_kernel(const float* __restrict__ z, const float* __restrict__ emb,
                       const float* __restrict__ idxf,
                       float* __restrict__ out_q, float* __restrict__ out_loss)
{
    __shared__ float zts[32 * 257];
    __shared__ int   ids[32];

    const int t  = threadIdx.x;
    const int bh = blockIdx.x;
    const int b  = bh >> 5, h = bh & 31;
    const int n0 = bh * 32;

    if (t < 32) ids[t] = (int)idxf[n0 + t];
    __syncthreads();

    const size_t zbase = (size_t)b * (ZC * 1024) + h * 32;

    for (int rep = 0; rep < 32; ++rep) {
        const int flat = rep * 256 + t;
        const int c = flat >> 5;
        const int ww = flat & 31;
        const size_t ga = zbase + (size_t)c * 1024 + ww;
        const float zv = z[ga];
        zts[ww * 257 + c] = zv;
        out_q[ga] = emb[(size_t)ids[ww] * ZC + c];
    }
    __syncthreads();

    for (int rep = 0; rep < 32; ++rep) {
        const float e = emb[(size_t)ids[rep] * ZC + t];
        const float d = e - zts[rep * 257 + t];
        out_loss[(size_t)(n0 + rep) * ZC + t] = 1.25f * d * d;
    }
}

extern "C" void kernel_launch(void* const* d_in, const int* in_sizes, int n_in,
                              void* d_out, int out_size, void* d_ws, size_t ws_size,
                              hipStream_t stream)
{
    const float* z   = (const float*)d_in[0];   // [32,256,32,32]
    const float* emb = (const float*)d_in[1];   // [1024,256]
    float* out      = (float*)d_out;
    float* out_q    = out;                       // 8388608 floats
    float* out_loss = out + 8388608;             // 8388608 floats
    float* out_idx  = out + 16777216;            // 32768 floats

    // scratch carved from output regions (fully overwritten by final kernels):
    unsigned short* Ab = (unsigned short*)d_out;                       // 16 MiB (out_q)
    unsigned short* Bb = (unsigned short*)((char*)d_out + 33554432);   // 512 KiB
    float* ensg = (float*)((char*)d_out + 34603008);                   // 4 KiB
    int*   cnt  = (int*)  ((char*)d_out + 34607104);                   // 4 B
    int*   list = (int*)  ((char*)d_out + 34607168);                   // 128 KiB
    float* pV1  = (float*)((char*)d_out + 34738240);                   // 256 KiB
    float* pV2  = (float*)((char*)d_out + 35000384);                   // 256 KiB
    int*   pI   = (int*)  ((char*)d_out + 35262528);                   // 256 KiB

    vq_prep_z        <<<4096, 256, 0, stream>>>(z, Ab);
    vq_prep_e        <<<128,  256, 0, stream>>>(emb, Bb);
    vq_ens_np        <<<32,   256, 0, stream>>>(emb, ensg, cnt);
    vq_gemm_argmin   <<<1024, 256, 0, stream>>>(Ab, Bb, ensg, pV1, pV2, pI);
    vq_merge         <<<128,  256, 0, stream>>>(pV1, pV2, pI, out_idx);
    vq_compact       <<<128,  256, 0, stream>>>(out_idx, cnt, list);
    vq_fixup6        <<<8192, 256, 0, stream>>>(z, emb, ensg, out_idx, cnt, list);
    vq_outputs_kernel<<<1024, 256, 0, stream>>>(z, emb, out_idx, out_q, out_loss);
}

// Round 18
// 187.613 us; speedup vs baseline: 1.0491x; 1.0491x over previous
//
#include <hip/hip_runtime.h>

#define ZC     256
#define KCODES 1024
#define MARGIN 4e-4f   // hi-only bf16 GEMM: gap-error sigma ~4e-5 -> 10 sigma
#define WIN    1e-4f   // screen->candidate window (bound ~3.2e-5, 3x headroom)

typedef __attribute__((ext_vector_type(4))) float f32x4;
typedef __attribute__((ext_vector_type(8))) short s16x8;
typedef unsigned int u32t;
typedef u32t __attribute__((address_space(1))) as1_u32;
typedef u32t __attribute__((address_space(3))) as3_u32;

__device__ __forceinline__ void glds16(const void* g, void* l) {
    __builtin_amdgcn_global_load_lds((const as1_u32*)g, (as3_u32*)l, 16, 0, 0);
}
__device__ __forceinline__ unsigned short bf16_rn(float x) {
    union { float f; u32t u; } v; v.f = x;
    return (unsigned short)((v.u + 0x7FFFu + ((v.u >> 16) & 1u)) >> 16);
}

// ---------------------------------------------------------------------------
// prep_z (verified r12-r17): z -> A' bf16 [4 kblk][32768 pt][64 k], swizzled
// short col = k ^ ((pt&7)<<3).
// ---------------------------------------------------------------------------
__global__ __launch_bounds__(256)
void vq_prep_z(const float* __restrict__ z, unsigned short* __restrict__ Ab)
{
    const int t = threadIdx.x, blk = blockIdx.x;
    const int pt = (blk >> 3) * 64 + (t & 63);
    const int c0 = (blk & 7) * 32 + (t >> 6) * 8;
    const int b = pt >> 10, hw = pt & 1023;
    const float* zp = z + (size_t)b * (ZC * 1024) + (size_t)c0 * 1024 + hw;

    unsigned short hi[8];
    #pragma unroll
    for (int j = 0; j < 8; ++j) hi[j] = bf16_rn(zp[(size_t)j * 1024]);
    uint4 ph;
    ph.x = (u32t)hi[0] | ((u32t)hi[1] << 16); ph.y = (u32t)hi[2] | ((u32t)hi[3] << 16);
    ph.z = (u32t)hi[4] | ((u32t)hi[5] << 16); ph.w = (u32t)hi[6] | ((u32t)hi[7] << 16);

    const size_t kb = (size_t)(c0 >> 6);
    const int sw = (c0 & 63) ^ ((pt & 7) << 3);
    *reinterpret_cast<uint4*>(Ab + kb * (32768ull * 64) + (size_t)pt * 64 + sw) = ph;
}

// ---------------------------------------------------------------------------
// prep_e (verified r12-r17): emb -> B' bf16 [4 kblk][1024 code][64], swizzled.
// ---------------------------------------------------------------------------
__global__ __launch_bounds__(256)
void vq_prep_e(const float* __restrict__ emb, unsigned short* __restrict__ Bb)
{
    const int t = threadIdx.x, blk = blockIdx.x;
    const int code = (blk >> 3) * 64 + (t & 63);
    const int c0 = (blk & 7) * 32 + (t >> 6) * 8;
    const float* ep = emb + (size_t)code * ZC + c0;

    unsigned short hi[8];
    #pragma unroll
    for (int j = 0; j < 8; ++j) hi[j] = bf16_rn(ep[j]);
    uint4 ph;
    ph.x = (u32t)hi[0] | ((u32t)hi[1] << 16); ph.y = (u32t)hi[2] | ((u32t)hi[3] << 16);
    ph.z = (u32t)hi[4] | ((u32t)hi[5] << 16); ph.w = (u32t)hi[6] | ((u32t)hi[7] << 16);

    const size_t kb = (size_t)(c0 >> 6);
    const int sw = (c0 & 63) ^ ((code & 7) << 3);
    *reinterpret_cast<uint4*>(Bb + kb * (1024ull * 64) + (size_t)code * 64 + sw) = ph;
}

// ---------------------------------------------------------------------------
// ens_np (verified r13-r17): np-pairwise-exact codebook norms; zeroes counter.
// ---------------------------------------------------------------------------
__global__ __launch_bounds__(256)
void vq_ens_np(const float* __restrict__ emb, float* __restrict__ ens_np,
               int* __restrict__ cnt)
{
    if (blockIdx.x == 0 && threadIdx.x == 0) *cnt = 0;
    const int t = threadIdx.x, g = t >> 3, r = t & 7;
    const int code = blockIdx.x * 32 + g;
    const float* er = emb + (size_t)code * ZC;

    float lo, hi;
    {
        const float a0 = er[r], a1 = er[128 + r];
        lo = __fmul_rn(a0, a0); hi = __fmul_rn(a1, a1);
    }
    #pragma unroll
    for (int i = 1; i < 16; ++i) {
        const int c = 8 * i + r;
        const float a0 = er[c], a1 = er[128 + c];
        lo = __fadd_rn(lo, __fmul_rn(a0, a0));
        hi = __fadd_rn(hi, __fmul_rn(a1, a1));
    }
    #pragma unroll
    for (int mk = 1; mk < 8; mk <<= 1) {
        lo = __fadd_rn(lo, __shfl_xor(lo, mk));
        hi = __fadd_rn(hi, __shfl_xor(hi, mk));
    }
    if (r == 0) ens_np[code] = __fadd_rn(lo, hi);
}

// ---------------------------------------------------------------------------
// GEMM+argmin: r16 config (512 blocks, 64 pts x 1024 codes, direct out_idx —
// r17's split regressed, reverted) with BK=128 phases: stage 2 kblk planes
// per barrier pair -> 16 phases instead of 32 (r7-vs-r16 fit shows cost is
// per-phase fixed, ~2.6us/phase at 2 blocks/CU). LDS 48 KB (A 16 + B 32).
// Compute consumes (plane,sub) pairs sequentially -> register pressure LOWER
// than r16 (6 live s16x8 vs 12). Epilogue/merges byte-identical to r12-r16.
// ---------------------------------------------------------------------------
__global__ __launch_bounds__(256, 2)
void vq_gemm_argmin(const unsigned short* __restrict__ Ab,
                    const unsigned short* __restrict__ Bb,
                    const float* __restrict__ ens_g, float* __restrict__ out_idx)
{
    __shared__ unsigned short As[2 * 4096];    // 16 KB: 2 planes x (64 rows x 64)
    __shared__ unsigned short Bs[2 * 8192];    // 32 KB: 2 planes x (128 rows x 64)

    const int t = threadIdx.x;
    const int lane = t & 63, wv = t >> 6;
    const int col = lane & 15, kg = lane >> 4;
    const int pt0 = blockIdx.x * 64;
    const int kx = (col & 7) << 3;             // read-side XOR (shorts)

    // per-(m|n, sub) offsets within a plane (shorts)
    int aoff[4][2], boff[2][2];
    #pragma unroll
    for (int m = 0; m < 4; ++m)
        #pragma unroll
        for (int s = 0; s < 2; ++s)
            aoff[m][s] = (m * 16 + col) * 64 + ((s * 32 + kg * 8) ^ kx);
    #pragma unroll
    for (int n = 0; n < 2; ++n)
        #pragma unroll
        for (int s = 0; s < 2; ++s)
            boff[n][s] = (wv * 32 + n * 16 + col) * 64 + ((s * 32 + kg * 8) ^ kx);

    f32x4 acc[4][2];
    #pragma unroll
    for (int m = 0; m < 4; ++m)
        #pragma unroll
        for (int n = 0; n < 2; ++n) acc[m][n] = (f32x4){0.f, 0.f, 0.f, 0.f};

    float v1[16], v2[16]; int id1[16];
    #pragma unroll
    for (int i = 0; i < 16; ++i) { v1[i] = 3.4e38f; v2[i] = 3.4e38f; id1[i] = 0; }

    for (int ct = 0; ct < 8; ++ct) {
        for (int kh = 0; kh < 2; ++kh) {       // 2 phases per ct, BK=128 each
            __syncthreads();   // prior phase's LDS reads complete
            #pragma unroll
            for (int pl = 0; pl < 2; ++pl) {
                const int ks = kh * 2 + pl;    // kblk plane 0..3
                const char* aS = (const char*)(Ab + (size_t)ks * 2097152ull + (size_t)pt0 * 64);
                const char* bS = (const char*)(Bb + (size_t)ks * 65536ull + (size_t)ct * 8192);
                glds16(aS + t * 16,        (char*)As + pl * 8192 + t * 16);
                glds16(aS + 4096 + t * 16, (char*)As + pl * 8192 + 4096 + t * 16);
                #pragma unroll
                for (int q = 0; q < 4; ++q)
                    glds16(bS + q * 4096 + t * 16, (char*)Bs + pl * 16384 + q * 4096 + t * 16);
            }
            __syncthreads();   // drains vmcnt before barrier

            #pragma unroll
            for (int pl = 0; pl < 2; ++pl) {
                #pragma unroll
                for (int s = 0; s < 2; ++s) {
                    s16x8 af[4], bf[2];
                    #pragma unroll
                    for (int m = 0; m < 4; ++m)
                        af[m] = *reinterpret_cast<const s16x8*>(As + pl * 4096 * 1 * 2 / 2 * 2 + 0);
                    // (placeholder removed below — real reads follow)
                    (void)af; (void)bf;
                }
            }
            // --- real compute (the block above is never what we want; do it plainly) ---
            #pragma unroll
            for (int pl = 0; pl < 2; ++pl) {
                const unsigned short* ap = As + pl * 4096;
                const unsigned short* bp = Bs + pl * 8192;
                #pragma unroll
                for (int s = 0; s < 2; ++s) {
                    s16x8 af0 = *reinterpret_cast<const s16x8*>(ap + aoff[0][s]);
                    s16x8 af1 = *reinterpret_cast<const s16x8*>(ap + aoff[1][s]);
                    s16x8 af2 = *reinterpret_cast<const s16x8*>(ap + aoff[2][s]);
                    s16x8 af3 = *reinterpret_cast<const s16x8*>(ap + aoff[3][s]);
                    s16x8 bf0 = *reinterpret_cast<const s16x8*>(bp + boff[0][s]);
                    s16x8 bf1 = *reinterpret_cast<const s16x8*>(bp + boff[1][s]);
                    acc[0][0] = __builtin_amdgcn_mfma_f32_16x16x32_bf16(af0, bf0, acc[0][0], 0, 0, 0);
                    acc[0][1] = __builtin_amdgcn_mfma_f32_16x16x32_bf16(af0, bf1, acc[0][1], 0, 0, 0);
                    acc[1][0] = __builtin_amdgcn_mfma_f32_16x16x32_bf16(af1, bf0, acc[1][0], 0, 0, 0);
                    acc[1][1] = __builtin_amdgcn_mfma_f32_16x16x32_bf16(af1, bf1, acc[1][1], 0, 0, 0);
                    acc[2][0] = __builtin_amdgcn_mfma_f32_16x16x32_bf16(af2, bf0, acc[2][0], 0, 0, 0);
                    acc[2][1] = __builtin_amdgcn_mfma_f32_16x16x32_bf16(af2, bf1, acc[2][1], 0, 0, 0);
                    acc[3][0] = __builtin_amdgcn_mfma_f32_16x16x32_bf16(af3, bf0, acc[3][0], 0, 0, 0);
                    acc[3][1] = __builtin_amdgcn_mfma_f32_16x16x32_bf16(af3, bf1, acc[3][1], 0, 0, 0);
                }
            }

            if (kh == 1) {   // full K=256 done for this ct: top-2 update, reset acc
                #pragma unroll
                for (int n = 0; n < 2; ++n) {
                    const int code = ct * 128 + wv * 32 + n * 16 + col;
                    const float en = ens_g[code];
                    #pragma unroll
                    for (int m = 0; m < 4; ++m)
                        #pragma unroll
                        for (int j = 0; j < 4; ++j) {
                            const float sc = fmaf(-2.f, acc[m][n][j], en);
                            const int sl = m * 4 + j;
                            if (sc < v1[sl]) { v2[sl] = v1[sl]; v1[sl] = sc; id1[sl] = code; }
                            else if (sc < v2[sl]) { v2[sl] = sc; }
                            acc[m][n][j] = 0.f;
                        }
                }
            }
        }
    }

    // in-wave 16-lane top-2 merge (verified rounds 5-17)
    float w1[16], w2[16]; int wid[16];
    #pragma unroll
    for (int sl = 0; sl < 16; ++sl) {
        float a1 = v1[sl]; int ai = id1[sl]; float a2 = v2[sl];
        #pragma unroll
        for (int mk = 1; mk < 16; mk <<= 1) {
            const float o1 = __shfl_xor(a1, mk);
            const int   oi = __shfl_xor(ai, mk);
            const float o2 = __shfl_xor(a2, mk);
            if (o1 < a1)      { a2 = fminf(a1, o2); a1 = o1; ai = oi; }
            else if (o1 > a1) { a2 = fminf(a2, o1); }
            else              { a2 = (oi != ai) ? a1 : fminf(a2, o2); ai = (oi < ai) ? oi : ai; }
        }
        w1[sl] = a1; w2[sl] = a2; wid[sl] = ai;
    }

    // cross-wave merge via LDS (verified rounds 5-17)
    __syncthreads();
    float* mv1 = reinterpret_cast<float*>(As);
    float* mv2 = mv1 + 256;
    int*   mid = reinterpret_cast<int*>(mv2 + 256);
    if (col == 0) {
        #pragma unroll
        for (int sl = 0; sl < 16; ++sl) {
            const int m = sl >> 2, j = sl & 3;
            const int p = m * 16 + kg * 4 + j;
            mv1[wv * 64 + p] = w1[sl];
            mv2[wv * 64 + p] = w2[sl];
            mid[wv * 64 + p] = wid[sl];
        }
    }
    __syncthreads();
    if (t < 64) {
        float a1 = mv1[t], a2 = mv2[t]; int ai = mid[t];
        #pragma unroll
        for (int w = 1; w < 4; ++w) {
            const float b1 = mv1[w * 64 + t], b2 = mv2[w * 64 + t];
            const int   bi = mid[w * 64 + t];
            if (b1 < a1)      { a2 = fminf(a1, b2); a1 = b1; ai = bi; }
            else if (b1 > a1) { a2 = fminf(a2, b1); }
            else              { a2 = a1; ai = (bi < ai) ? bi : ai; }
        }
        out_idx[pt0 + t] = ((a2 - a1) <= MARGIN) ? (-1.0f - (float)ai) : (float)ai;
    }
}

// ---------------------------------------------------------------------------
// compact: flagged points -> worklist.
// ---------------------------------------------------------------------------
__global__ __launch_bounds__(256)
void vq_compact(const float* __restrict__ idxf, int* __restrict__ cnt,
                int* __restrict__ list)
{
    const int n = blockIdx.x * 256 + threadIdx.x;
    if (idxf[n] < 0.f) { const int p = atomicAdd(cnt, 1); list[p] = n; }
}

// ---------------------------------------------------------------------------
// fixup6 (verified r16/r17): reg-dbuf f32 screen + candidate collection +
// f64 np-exact adjudication. Unchanged.
// ---------------------------------------------------------------------------
__global__ __launch_bounds__(256, 1)
void vq_fixup6(const float* __restrict__ z, const float* __restrict__ emb,
               const float* __restrict__ ens_np, float* __restrict__ idxf,
               const int* __restrict__ cnt, const int* __restrict__ list)
{
    __shared__ float  zsb[4 * 264];
    __shared__ float  scr[4 * 1024];
    __shared__ float  znv[4];
    __shared__ float  smin[4];
    __shared__ int    pn[4];
    __shared__ float  redm[4];
    __shared__ int    candk[128];
    __shared__ int    candp[128];
    __shared__ int    ccnt;
    __shared__ double dred[4];
    __shared__ float  bestd_s[4];
    __shared__ int    bestk_s[4];

    const int t = threadIdx.x;
    const int g = t >> 3, r = t & 7;
    const int C = *cnt;
    const int base = blockIdx.x * 4;
    if (base >= C) return;
    const int npts = (C - base < 4) ? (C - base) : 4;

    if (t < 4) pn[t] = (base + t < C) ? list[base + t] : list[base];
    if (t == 0) ccnt = 0;
    __syncthreads();
    #pragma unroll
    for (int p = 0; p < 4; ++p) {
        const int n = pn[p];
        const int b = n >> 10, q = n & 1023;
        zsb[p * 264 + t] = z[(size_t)b * (ZC * 1024) + (size_t)t * 1024 + q];
    }
    __syncthreads();

    if (t < 32) {
        const float* zp = zsb + g * 264;
        float lo = __fmul_rn(zp[r], zp[r]);
        float hi = __fmul_rn(zp[128 + r], zp[128 + r]);
        #pragma unroll
        for (int i = 1; i < 16; ++i) {
            const int c = 8 * i + r;
            lo = __fadd_rn(lo, __fmul_rn(zp[c], zp[c]));
            hi = __fadd_rn(hi, __fmul_rn(zp[128 + c], zp[128 + c]));
        }
        #pragma unroll
        for (int mk = 1; mk < 8; mk <<= 1) {
            lo = __fadd_rn(lo, __shfl_xor(lo, mk));
            hi = __fadd_rn(hi, __shfl_xor(hi, mk));
        }
        if (r == 0) znv[g] = __fadd_rn(lo, hi);
    }

    const float* zb0 = zsb + 0 * 264 + r * 4;
    const float* zb1 = zsb + 1 * 264 + r * 4;
    const float* zb2 = zsb + 2 * 264 + r * 4;
    const float* zb3 = zsb + 3 * 264 + r * 4;

    float4 eA0, eA1, eA2, eA3, eA4, eA5, eA6, eA7;
    {
        const float* er = emb + (size_t)g * ZC + r * 4;
        eA0 = *reinterpret_cast<const float4*>(er);
        eA1 = *reinterpret_cast<const float4*>(er + 32);
        eA2 = *reinterpret_cast<const float4*>(er + 64);
        eA3 = *reinterpret_cast<const float4*>(er + 96);
        eA4 = *reinterpret_cast<const float4*>(er + 128);
        eA5 = *reinterpret_cast<const float4*>(er + 160);
        eA6 = *reinterpret_cast<const float4*>(er + 192);
        eA7 = *reinterpret_cast<const float4*>(er + 224);
    }

    for (int tile = 0; tile < 32; ++tile) {
        float4 eB0, eB1, eB2, eB3, eB4, eB5, eB6, eB7;
        if (tile < 31) {
            const float* er = emb + (size_t)(tile + 1) * 32 * ZC + (size_t)g * ZC + r * 4;
            eB0 = *reinterpret_cast<const float4*>(er);
            eB1 = *reinterpret_cast<const float4*>(er + 32);
            eB2 = *reinterpret_cast<const float4*>(er + 64);
            eB3 = *reinterpret_cast<const float4*>(er + 96);
            eB4 = *reinterpret_cast<const float4*>(er + 128);
            eB5 = *reinterpret_cast<const float4*>(er + 160);
            eB6 = *reinterpret_cast<const float4*>(er + 192);
            eB7 = *reinterpret_cast<const float4*>(er + 224);
        }

        float s0 = 0.f, s1 = 0.f, s2 = 0.f, s3 = 0.f;
        #define SCREEN_STEP(EV, OFF)                                           \
        {                                                                      \
            const float4 a0 = *reinterpret_cast<const float4*>(zb0 + (OFF));   \
            const float4 a1 = *reinterpret_cast<const float4*>(zb1 + (OFF));   \
            const float4 a2 = *reinterpret_cast<const float4*>(zb2 + (OFF));   \
            const float4 a3 = *reinterpret_cast<const float4*>(zb3 + (OFF));   \
            s0 = fmaf(EV.x, a0.x, s0); s0 = fmaf(EV.y, a0.y, s0);              \
            s0 = fmaf(EV.z, a0.z, s0); s0 = fmaf(EV.w, a0.w, s0);              \
            s1 = fmaf(EV.x, a1.x, s1); s1 = fmaf(EV.y, a1.y, s1);              \
            s1 = fmaf(EV.z, a1.z, s1); s1 = fmaf(EV.w, a1.w, s1);              \
            s2 = fmaf(EV.x, a2.x, s2); s2 = fmaf(EV.y, a2.y, s2);              \
            s2 = fmaf(EV.z, a2.z, s2); s2 = fmaf(EV.w, a2.w, s2);              \
            s3 = fmaf(EV.x, a3.x, s3); s3 = fmaf(EV.y, a3.y, s3);              \
            s3 = fmaf(EV.z, a3.z, s3); s3 = fmaf(EV.w, a3.w, s3);              \
        }
        SCREEN_STEP(eA0, 0)
        SCREEN_STEP(eA1, 32)
        SCREEN_STEP(eA2, 64)
        SCREEN_STEP(eA3, 96)
        SCREEN_STEP(eA4, 128)
        SCREEN_STEP(eA5, 160)
        SCREEN_STEP(eA6, 192)
        SCREEN_STEP(eA7, 224)
        #undef SCREEN_STEP

        #pragma unroll
        for (int mk = 1; mk < 8; mk <<= 1) {
            s0 += __shfl_xor(s0, mk);
            s1 += __shfl_xor(s1, mk);
            s2 += __shfl_xor(s2, mk);
            s3 += __shfl_xor(s3, mk);
        }
        if (r == 0) {
            const int code = tile * 32 + g;
            const float en = ens_np[code];
            scr[0 * 1024 + code] = fmaf(-2.f, s0, en);
            scr[1 * 1024 + code] = fmaf(-2.f, s1, en);
            scr[2 * 1024 + code] = fmaf(-2.f, s2, en);
            scr[3 * 1024 + code] = fmaf(-2.f, s3, en);
        }

        eA0 = eB0; eA1 = eB1; eA2 = eB2; eA3 = eB3;
        eA4 = eB4; eA5 = eB5; eA6 = eB6; eA7 = eB7;
    }
    __syncthreads();

    for (int p = 0; p < 4; ++p) {
        float m = fminf(fminf(scr[p * 1024 + t],       scr[p * 1024 + t + 256]),
                        fminf(scr[p * 1024 + t + 512], scr[p * 1024 + t + 768]));
        #pragma unroll
        for (int mk = 1; mk < 64; mk <<= 1) m = fminf(m, __shfl_xor(m, mk));
        if ((t & 63) == 0) redm[t >> 6] = m;
        __syncthreads();
        if (t == 0) smin[p] = fminf(fminf(redm[0], redm[1]), fminf(redm[2], redm[3]));
        __syncthreads();
    }

    for (int p = 0; p < 4; ++p) {
        #pragma unroll
        for (int rep = 0; rep < 4; ++rep) {
            const int code = rep * 256 + t;
            if (scr[p * 1024 + code] <= smin[p] + WIN) {
                const int pos = atomicAdd(&ccnt, 1);
                if (pos < 128) { candk[pos] = code; candp[pos] = p; }
            }
        }
    }
    __syncthreads();
    const int NC = (ccnt < 128) ? ccnt : 128;

    if (t < 4) { bestd_s[t] = 3.4e38f; bestk_s[t] = 0x7fffffff; }
    __syncthreads();
    for (int ci = 0; ci < NC; ++ci) {
        const int code = candk[ci], p = candp[ci];
        double dd = (double)emb[(size_t)code * ZC + t] * (double)zsb[p * 264 + t];
        #pragma unroll
        for (int mk = 1; mk < 64; mk <<= 1) dd = dd + __shfl_xor(dd, mk);
        if ((t & 63) == 0) dred[t >> 6] = dd;
        __syncthreads();
        if (t == 0) {
            const double tot = (dred[0] + dred[1]) + (dred[2] + dred[3]);
            const float t2f = (float)tot;
            const float d = __fsub_rn(__fadd_rn(znv[p], ens_np[code]),
                                      __fmul_rn(2.0f, t2f));
            if (d < bestd_s[p] || (d == bestd_s[p] && code < bestk_s[p])) {
                bestd_s[p] = d; bestk_s[p] = code;
            }
        }
        __syncthreads();
    }
    if (t < npts) idxf[pn[t]] = (float)bestk_s[t];
}

// ---------------------------------------------------------------------------
// outputs (verified round 2) — overwrites the scratch regions.
// ---------------------------------------------------------------------------
__global__ __launch_bounds__(256)
void vq_outputs_kernel(const float* __restrict__ z, const float* __restrict__ emb,
                       const float* __restrict__ idxf,
                       float* __restrict__ out_q, float* __restrict__ out_loss)
{
    __shared__ float zts[32 * 257];
    __shared__ int   ids[32];

    const int t  = threadIdx.x;
    const int bh = blockIdx.x;
    const int b  = bh >> 5, h = bh & 31;
    const int n0 = bh * 32;

    if (t < 32) ids[t] = (int)idxf[n0 + t];
    __syncthreads();

    const size_t zbase = (size_t)b * (ZC * 1024) + h * 32;

    for (int rep = 0; rep < 32; ++rep) {
        const int flat = rep * 256 + t;
        const int c = flat >> 5;
        const int ww = flat & 31;
        const size_t ga = zbase + (size_t)c * 1024 + ww;
        const float zv = z[ga];
        zts[ww * 257 + c] = zv;
        out_q[ga] = emb[(size_t)ids[ww] * ZC + c];
    }
    __syncthreads();

    for (int rep = 0; rep < 32; ++rep) {
        const float e = emb[(size_t)ids[rep] * ZC + t];
        const float d = e - zts[rep * 257 + t];
        out_loss[(size_t)(n0 + rep) * ZC + t] = 1.25f * d * d;
    }
}

extern "C" void kernel_launch(void* const* d_in, const int* in_sizes, int n_in,
                              void* d_out, int out_size, void* d_ws, size_t ws_size,
                              hipStream_t stream)
{
    const float* z   = (const float*)d_in[0];   // [32,256,32,32]
    const float* emb = (const float*)d_in[1];   // [1024,256]
    float* out      = (float*)d_out;
    float* out_q    = out;                       // 8388608 floats
    float* out_loss = out + 8388608;             // 8388608 floats
    float* out_idx  = out + 16777216;            // 32768 floats

    // scratch carved from output regions (fully overwritten by final kernels):
    unsigned short* Ab = (unsigned short*)d_out;                       // 16 MiB (out_q)
    unsigned short* Bb = (unsigned short*)((char*)d_out + 33554432);   // 512 KiB
    float* ensg = (float*)((char*)d_out + 34603008);                   // 4 KiB
    int*   cnt  = (int*)  ((char*)d_out + 34607104);                   // 4 B
    int*   list = (int*)  ((char*)d_out + 34607168);                   // 128 KiB

    vq_prep_z        <<<4096, 256, 0, stream>>>(z, Ab);
    vq_prep_e        <<<128,  256, 0, stream>>>(emb, Bb);
    vq_ens_np        <<<32,   256, 0, stream>>>(emb, ensg, cnt);
    vq_gemm_argmin   <<<512,  256, 0, stream>>>(Ab, Bb, ensg, out_idx);
    vq_compact       <<<128,  256, 0, stream>>>(out_idx, cnt, list);
    vq_fixup6        <<<8192, 256, 0, stream>>>(z, emb, ensg, out_idx, cnt, list);
    vq_outputs_kernel<<<1024, 256, 0, stream>>>(z, emb, out_idx, out_q, out_loss);
}

// Round 19
// 182.605 us; speedup vs baseline: 1.0779x; 1.0274x over previous
//
#include <hip/hip_runtime.h>

#define ZC     256
#define KCODES 1024
#define MARGIN 4e-4f   // hi-only bf16 GEMM: gap-error sigma ~4e-5 -> 10 sigma
#define WIN    1e-4f   // screen->candidate window (bound ~3.2e-5, 3x headroom)
#define NPT    32768

typedef __attribute__((ext_vector_type(4))) float f32x4;
typedef __attribute__((ext_vector_type(8))) short s16x8;
typedef unsigned int u32t;
typedef u32t __attribute__((address_space(1))) as1_u32;
typedef u32t __attribute__((address_space(3))) as3_u32;

__device__ __forceinline__ void glds16(const void* g, void* l) {
    __builtin_amdgcn_global_load_lds((const as1_u32*)g, (as3_u32*)l, 16, 0, 0);
}
__device__ __forceinline__ unsigned short bf16_rn(float x) {
    union { float f; u32t u; } v; v.f = x;
    return (unsigned short)((v.u + 0x7FFFu + ((v.u >> 16) & 1u)) >> 16);
}

// ---------------------------------------------------------------------------
// prep_z (verified r12-r18): z -> A' bf16 [4 kblk][32768 pt][64 k], swizzled.
// ---------------------------------------------------------------------------
__global__ __launch_bounds__(256)
void vq_prep_z(const float* __restrict__ z, unsigned short* __restrict__ Ab)
{
    const int t = threadIdx.x, blk = blockIdx.x;
    const int pt = (blk >> 3) * 64 + (t & 63);
    const int c0 = (blk & 7) * 32 + (t >> 6) * 8;
    const int b = pt >> 10, hw = pt & 1023;
    const float* zp = z + (size_t)b * (ZC * 1024) + (size_t)c0 * 1024 + hw;

    unsigned short hi[8];
    #pragma unroll
    for (int j = 0; j < 8; ++j) hi[j] = bf16_rn(zp[(size_t)j * 1024]);
    uint4 ph;
    ph.x = (u32t)hi[0] | ((u32t)hi[1] << 16); ph.y = (u32t)hi[2] | ((u32t)hi[3] << 16);
    ph.z = (u32t)hi[4] | ((u32t)hi[5] << 16); ph.w = (u32t)hi[6] | ((u32t)hi[7] << 16);

    const size_t kb = (size_t)(c0 >> 6);
    const int sw = (c0 & 63) ^ ((pt & 7) << 3);
    *reinterpret_cast<uint4*>(Ab + kb * (32768ull * 64) + (size_t)pt * 64 + sw) = ph;
}

// ---------------------------------------------------------------------------
// prep_e (verified r12-r18): emb -> B' bf16 [4 kblk][1024 code][64], swizzled.
// ---------------------------------------------------------------------------
__global__ __launch_bounds__(256)
void vq_prep_e(const float* __restrict__ emb, unsigned short* __restrict__ Bb)
{
    const int t = threadIdx.x, blk = blockIdx.x;
    const int code = (blk >> 3) * 64 + (t & 63);
    const int c0 = (blk & 7) * 32 + (t >> 6) * 8;
    const float* ep = emb + (size_t)code * ZC + c0;

    unsigned short hi[8];
    #pragma unroll
    for (int j = 0; j < 8; ++j) hi[j] = bf16_rn(ep[j]);
    uint4 ph;
    ph.x = (u32t)hi[0] | ((u32t)hi[1] << 16); ph.y = (u32t)hi[2] | ((u32t)hi[3] << 16);
    ph.z = (u32t)hi[4] | ((u32t)hi[5] << 16); ph.w = (u32t)hi[6] | ((u32t)hi[7] << 16);

    const size_t kb = (size_t)(c0 >> 6);
    const int sw = (c0 & 63) ^ ((code & 7) << 3);
    *reinterpret_cast<uint4*>(Bb + kb * (1024ull * 64) + (size_t)code * 64 + sw) = ph;
}

// ---------------------------------------------------------------------------
// ens_np (verified r13-r18): np-pairwise-exact codebook norms; zeroes counter.
// ---------------------------------------------------------------------------
__global__ __launch_bounds__(256)
void vq_ens_np(const float* __restrict__ emb, float* __restrict__ ens_np,
               int* __restrict__ cnt)
{
    if (blockIdx.x == 0 && threadIdx.x == 0) *cnt = 0;
    const int t = threadIdx.x, g = t >> 3, r = t & 7;
    const int code = blockIdx.x * 32 + g;
    const float* er = emb + (size_t)code * ZC;

    float lo, hi;
    {
        const float a0 = er[r], a1 = er[128 + r];
        lo = __fmul_rn(a0, a0); hi = __fmul_rn(a1, a1);
    }
    #pragma unroll
    for (int i = 1; i < 16; ++i) {
        const int c = 8 * i + r;
        const float a0 = er[c], a1 = er[128 + c];
        lo = __fadd_rn(lo, __fmul_rn(a0, a0));
        hi = __fadd_rn(hi, __fmul_rn(a1, a1));
    }
    #pragma unroll
    for (int mk = 1; mk < 8; mk <<= 1) {
        lo = __fadd_rn(lo, __shfl_xor(lo, mk));
        hi = __fadd_rn(hi, __shfl_xor(hi, mk));
    }
    if (r == 0) ens_np[code] = __fadd_rn(lo, hi);
}

// ---------------------------------------------------------------------------
// GEMM+argmin: r16-verified inner k-step; top-2 state moved from 48 VGPRs to
// per-wave LDS rows (sv[wv][pt], rmw only by col==0 lanes of owning wave ->
// no races; merge algebra = r11-verified with old-codes<new-codes tie rule).
// Grid 1024 = (512 pt-tiles) x (2 code-halves): with the freed registers
// 4 blocks/CU can finally reside (r11/r17 failed at ~140 unified regs/wave).
// ---------------------------------------------------------------------------
__global__ __launch_bounds__(256, 2)
void vq_gemm_argmin(const unsigned short* __restrict__ Ab,
                    const unsigned short* __restrict__ Bb,
                    const float* __restrict__ ens_g,
                    float* __restrict__ partV1, float* __restrict__ partV2,
                    int* __restrict__ partI)
{
    __shared__ unsigned short As[64 * 64];     // 8 KB
    __shared__ unsigned short Bs[128 * 64];    // 16 KB
    __shared__ float sv1[4 * 64];              // per-wave top-2 state
    __shared__ float sv2[4 * 64];
    __shared__ int   sid[4 * 64];

    const int t = threadIdx.x;
    const int lane = t & 63, wv = t >> 6;
    const int col = lane & 15, kg = lane >> 4;
    const int blk = blockIdx.x;
    const int pt0 = (blk >> 1) * 64;
    const int half = blk & 1;
    const int kx = (col & 7) << 3;

    int aoff[4][2], boff[2][2];
    #pragma unroll
    for (int m = 0; m < 4; ++m)
        #pragma unroll
        for (int s = 0; s < 2; ++s)
            aoff[m][s] = (m * 16 + col) * 64 + ((s * 32 + kg * 8) ^ kx);
    #pragma unroll
    for (int n = 0; n < 2; ++n)
        #pragma unroll
        for (int s = 0; s < 2; ++s)
            boff[n][s] = (wv * 32 + n * 16 + col) * 64 + ((s * 32 + kg * 8) ^ kx);

    f32x4 acc[4][2];
    #pragma unroll
    for (int m = 0; m < 4; ++m)
        #pragma unroll
        for (int n = 0; n < 2; ++n) acc[m][n] = (f32x4){0.f, 0.f, 0.f, 0.f};

    // init this wave's state row (same-wave ordering; no barrier needed)
    sv1[wv * 64 + lane] = 3.4e38f;
    sv2[wv * 64 + lane] = 3.4e38f;
    sid[wv * 64 + lane] = 0x7fffffff;

    for (int ci = 0; ci < 4; ++ci) {
        const int ct = half * 4 + ci;
        for (int ks = 0; ks < 4; ++ks) {
            const char* aS = (const char*)(Ab + (size_t)ks * 2097152ull + (size_t)pt0 * 64);
            const char* bS = (const char*)(Bb + (size_t)ks * 65536ull + (size_t)ct * 8192);

            __syncthreads();   // prior k-step's LDS reads complete
            glds16(aS + t * 16,        (char*)As + t * 16);
            glds16(aS + 4096 + t * 16, (char*)As + 4096 + t * 16);
            #pragma unroll
            for (int q = 0; q < 4; ++q)
                glds16(bS + q * 4096 + t * 16, (char*)Bs + q * 4096 + t * 16);
            __syncthreads();   // drains vmcnt before barrier

            s16x8 af[4][2], bf[2][2];
            #pragma unroll
            for (int m = 0; m < 4; ++m)
                #pragma unroll
                for (int s = 0; s < 2; ++s)
                    af[m][s] = *reinterpret_cast<const s16x8*>(As + aoff[m][s]);
            #pragma unroll
            for (int n = 0; n < 2; ++n)
                #pragma unroll
                for (int s = 0; s < 2; ++s)
                    bf[n][s] = *reinterpret_cast<const s16x8*>(Bs + boff[n][s]);
            #pragma unroll
            for (int m = 0; m < 4; ++m)
                #pragma unroll
                for (int n = 0; n < 2; ++n) {
                    acc[m][n] = __builtin_amdgcn_mfma_f32_16x16x32_bf16(af[m][0], bf[n][0], acc[m][n], 0, 0, 0);
                    acc[m][n] = __builtin_amdgcn_mfma_f32_16x16x32_bf16(af[m][1], bf[n][1], acc[m][n], 0, 0, 0);
                }
        }

        // ---- ct epilogue: ct-local top-2 -> verified 16-lane butterfly ->
        //      col==0 rmw into this wave's LDS state (old codes < new codes)
        {
            const int code0 = ct * 128 + wv * 32 + col;
            const int code1 = code0 + 16;
            const float en0 = ens_g[code0];
            const float en1 = ens_g[code1];
            #pragma unroll
            for (int m = 0; m < 4; ++m)
                #pragma unroll
                for (int j = 0; j < 4; ++j) {
                    const float sc0 = fmaf(-2.f, acc[m][0][j], en0);
                    const float sc1 = fmaf(-2.f, acc[m][1][j], en1);
                    acc[m][0][j] = 0.f; acc[m][1][j] = 0.f;
                    float a1, a2; int ai;
                    if (sc0 <= sc1) { a1 = sc0; ai = code0; a2 = sc1; }
                    else            { a1 = sc1; ai = code1; a2 = sc0; }
                    #pragma unroll
                    for (int mk = 1; mk < 16; mk <<= 1) {
                        const float o1 = __shfl_xor(a1, mk);
                        const int   oi = __shfl_xor(ai, mk);
                        const float o2 = __shfl_xor(a2, mk);
                        if (o1 < a1)      { a2 = fminf(a1, o2); a1 = o1; ai = oi; }
                        else if (o1 > a1) { a2 = fminf(a2, o1); }
                        else              { a2 = (oi != ai) ? a1 : fminf(a2, o2); ai = (oi < ai) ? oi : ai; }
                    }
                    if (col == 0) {
                        const int idx = wv * 64 + m * 16 + kg * 4 + j;
                        const float o1 = sv1[idx], o2 = sv2[idx];
                        if (a1 < o1) {
                            sv1[idx] = a1; sid[idx] = ai; sv2[idx] = fminf(o1, a2);
                        } else {
                            // a1 >= o1: v1/id keep old (ties keep lower old code);
                            // second = min(o2, a1) (== o1 when tied)
                            sv2[idx] = fminf(o2, a1);
                        }
                    }
                }
        }
    }

    // final cross-wave fold (verbatim r17 algebra, source = LDS state rows)
    __syncthreads();
    if (t < 64) {
        float a1 = sv1[t], a2 = sv2[t]; int ai = sid[t];
        #pragma unroll
        for (int w = 1; w < 4; ++w) {
            const float b1 = sv1[w * 64 + t], b2 = sv2[w * 64 + t];
            const int   bi = sid[w * 64 + t];
            if (b1 < a1)      { a2 = fminf(a1, b2); a1 = b1; ai = bi; }
            else if (b1 > a1) { a2 = fminf(a2, b1); }
            else              { a2 = a1; ai = (bi < ai) ? bi : ai; }
        }
        const int g = half * NPT + pt0 + t;
        partV1[g] = a1; partV2[g] = a2; partI[g] = ai;
    }
}

// ---------------------------------------------------------------------------
// merge (r11/r17-verified fold) + inline compact (replaces vq_compact).
// ---------------------------------------------------------------------------
__global__ __launch_bounds__(256)
void vq_merge(const float* __restrict__ partV1, const float* __restrict__ partV2,
              const int* __restrict__ partI, float* __restrict__ out_idx,
              int* __restrict__ cnt, int* __restrict__ list)
{
    const int n = blockIdx.x * 256 + threadIdx.x;
    const float a1 = partV1[n],       a2 = partV2[n];
    const int   ai = partI[n];
    const float b1 = partV1[NPT + n], b2 = partV2[NPT + n];
    const int   bi = partI[NPT + n];
    float v1f, v2f; int idf;
    if (b1 < a1)      { v1f = b1; idf = bi; v2f = fminf(a1, b2); }
    else if (b1 > a1) { v1f = a1; idf = ai; v2f = fminf(a2, b1); }
    else              { v1f = a1; idf = (bi < ai) ? bi : ai; v2f = a1; }
    const bool flag = (v2f - v1f) <= MARGIN;
    out_idx[n] = flag ? (-1.0f - (float)idf) : (float)idf;
    if (flag) { const int pos = atomicAdd(cnt, 1); list[pos] = n; }
}

// ---------------------------------------------------------------------------
// fixup6 (verified r16-r18): reg-dbuf f32 screen + candidate collection +
// f64 np-exact adjudication. Unchanged.
// ---------------------------------------------------------------------------
__global__ __launch_bounds__(256, 1)
void vq_fixup6(const float* __restrict__ z, const float* __restrict__ emb,
               const float* __restrict__ ens_np, float* __restrict__ idxf,
               const int* __restrict__ cnt, const int* __restrict__ list)
{
    __shared__ float  zsb[4 * 264];
    __shared__ float  scr[4 * 1024];
    __shared__ float  znv[4];
    __shared__ float  smin[4];
    __shared__ int    pn[4];
    __shared__ float  redm[4];
    __shared__ int    candk[128];
    __shared__ int    candp[128];
    __shared__ int    ccnt;
    __shared__ double dred[4];
    __shared__ float  bestd_s[4];
    __shared__ int    bestk_s[4];

    const int t = threadIdx.x;
    const int g = t >> 3, r = t & 7;
    const int C = *cnt;
    const int base = blockIdx.x * 4;
    if (base >= C) return;
    const int npts = (C - base < 4) ? (C - base) : 4;

    if (t < 4) pn[t] = (base + t < C) ? list[base + t] : list[base];
    if (t == 0) ccnt = 0;
    __syncthreads();
    #pragma unroll
    for (int p = 0; p < 4; ++p) {
        const int n = pn[p];
        const int b = n >> 10, q = n & 1023;
        zsb[p * 264 + t] = z[(size_t)b * (ZC * 1024) + (size_t)t * 1024 + q];
    }
    __syncthreads();

    if (t < 32) {
        const float* zp = zsb + g * 264;
        float lo = __fmul_rn(zp[r], zp[r]);
        float hi = __fmul_rn(zp[128 + r], zp[128 + r]);
        #pragma unroll
        for (int i = 1; i < 16; ++i) {
            const int c = 8 * i + r;
            lo = __fadd_rn(lo, __fmul_rn(zp[c], zp[c]));
            hi = __fadd_rn(hi, __fmul_rn(zp[128 + c], zp[128 + c]));
        }
        #pragma unroll
        for (int mk = 1; mk < 8; mk <<= 1) {
            lo = __fadd_rn(lo, __shfl_xor(lo, mk));
            hi = __fadd_rn(hi, __shfl_xor(hi, mk));
        }
        if (r == 0) znv[g] = __fadd_rn(lo, hi);
    }

    const float* zb0 = zsb + 0 * 264 + r * 4;
    const float* zb1 = zsb + 1 * 264 + r * 4;
    const float* zb2 = zsb + 2 * 264 + r * 4;
    const float* zb3 = zsb + 3 * 264 + r * 4;

    float4 eA0, eA1, eA2, eA3, eA4, eA5, eA6, eA7;
    {
        const float* er = emb + (size_t)g * ZC + r * 4;
        eA0 = *reinterpret_cast<const float4*>(er);
        eA1 = *reinterpret_cast<const float4*>(er + 32);
        eA2 = *reinterpret_cast<const float4*>(er + 64);
        eA3 = *reinterpret_cast<const float4*>(er + 96);
        eA4 = *reinterpret_cast<const float4*>(er + 128);
        eA5 = *reinterpret_cast<const float4*>(er + 160);
        eA6 = *reinterpret_cast<const float4*>(er + 192);
        eA7 = *reinterpret_cast<const float4*>(er + 224);
    }

    for (int tile = 0; tile < 32; ++tile) {
        float4 eB0, eB1, eB2, eB3, eB4, eB5, eB6, eB7;
        if (tile < 31) {
            const float* er = emb + (size_t)(tile + 1) * 32 * ZC + (size_t)g * ZC + r * 4;
            eB0 = *reinterpret_cast<const float4*>(er);
            eB1 = *reinterpret_cast<const float4*>(er + 32);
            eB2 = *reinterpret_cast<const float4*>(er + 64);
            eB3 = *reinterpret_cast<const float4*>(er + 96);
            eB4 = *reinterpret_cast<const float4*>(er + 128);
            eB5 = *reinterpret_cast<const float4*>(er + 160);
            eB6 = *reinterpret_cast<const float4*>(er + 192);
            eB7 = *reinterpret_cast<const float4*>(er + 224);
        }

        float s0 = 0.f, s1 = 0.f, s2 = 0.f, s3 = 0.f;
        #define SCREEN_STEP(EV, OFF)                                           \
        {                                                                      \
            const float4 a0 = *reinterpret_cast<const float4*>(zb0 + (OFF));   \
            const float4 a1 = *reinterpret_cast<const float4*>(zb1 + (OFF));   \
            const float4 a2 = *reinterpret_cast<const float4*>(zb2 + (OFF));   \
            const float4 a3 = *reinterpret_cast<const float4*>(zb3 + (OFF));   \
            s0 = fmaf(EV.x, a0.x, s0); s0 = fmaf(EV.y, a0.y, s0);              \
            s0 = fmaf(EV.z, a0.z, s0); s0 = fmaf(EV.w, a0.w, s0);              \
            s1 = fmaf(EV.x, a1.x, s1); s1 = fmaf(EV.y, a1.y, s1);              \
            s1 = fmaf(EV.z, a1.z, s1); s1 = fmaf(EV.w, a1.w, s1);              \
            s2 = fmaf(EV.x, a2.x, s2); s2 = fmaf(EV.y, a2.y, s2);              \
            s2 = fmaf(EV.z, a2.z, s2); s2 = fmaf(EV.w, a2.w, s2);              \
            s3 = fmaf(EV.x, a3.x, s3); s3 = fmaf(EV.y, a3.y, s3);              \
            s3 = fmaf(EV.z, a3.z, s3); s3 = fmaf(EV.w, a3.w, s3);              \
        }
        SCREEN_STEP(eA0, 0)
        SCREEN_STEP(eA1, 32)
        SCREEN_STEP(eA2, 64)
        SCREEN_STEP(eA3, 96)
        SCREEN_STEP(eA4, 128)
        SCREEN_STEP(eA5, 160)
        SCREEN_STEP(eA6, 192)
        SCREEN_STEP(eA7, 224)
        #undef SCREEN_STEP

        #pragma unroll
        for (int mk = 1; mk < 8; mk <<= 1) {
            s0 += __shfl_xor(s0, mk);
            s1 += __shfl_xor(s1, mk);
            s2 += __shfl_xor(s2, mk);
            s3 += __shfl_xor(s3, mk);
        }
        if (r == 0) {
            const int code = tile * 32 + g;
            const float en = ens_np[code];
            scr[0 * 1024 + code] = fmaf(-2.f, s0, en);
            scr[1 * 1024 + code] = fmaf(-2.f, s1, en);
            scr[2 * 1024 + code] = fmaf(-2.f, s2, en);
            scr[3 * 1024 + code] = fmaf(-2.f, s3, en);
        }

        eA0 = eB0; eA1 = eB1; eA2 = eB2; eA3 = eB3;
        eA4 = eB4; eA5 = eB5; eA6 = eB6; eA7 = eB7;
    }
    __syncthreads();

    for (int p = 0; p < 4; ++p) {
        float m = fminf(fminf(scr[p * 1024 + t],       scr[p * 1024 + t + 256]),
                        fminf(scr[p * 1024 + t + 512], scr[p * 1024 + t + 768]));
        #pragma unroll
        for (int mk = 1; mk < 64; mk <<= 1) m = fminf(m, __shfl_xor(m, mk));
        if ((t & 63) == 0) redm[t >> 6] = m;
        __syncthreads();
        if (t == 0) smin[p] = fminf(fminf(redm[0], redm[1]), fminf(redm[2], redm[3]));
        __syncthreads();
    }

    for (int p = 0; p < 4; ++p) {
        #pragma unroll
        for (int rep = 0; rep < 4; ++rep) {
            const int code = rep * 256 + t;
            if (scr[p * 1024 + code] <= smin[p] + WIN) {
                const int pos = atomicAdd(&ccnt, 1);
                if (pos < 128) { candk[pos] = code; candp[pos] = p; }
            }
        }
    }
    __syncthreads();
    const int NC = (ccnt < 128) ? ccnt : 128;

    if (t < 4) { bestd_s[t] = 3.4e38f; bestk_s[t] = 0x7fffffff; }
    __syncthreads();
    for (int ci = 0; ci < NC; ++ci) {
        const int code = candk[ci], p = candp[ci];
        double dd = (double)emb[(size_t)code * ZC + t] * (double)zsb[p * 264 + t];
        #pragma unroll
        for (int mk = 1; mk < 64; mk <<= 1) dd = dd + __shfl_xor(dd, mk);
        if ((t & 63) == 0) dred[t >> 6] = dd;
        __syncthreads();
        if (t == 0) {
            const double tot = (dred[0] + dred[1]) + (dred[2] + dred[3]);
            const float t2f = (float)tot;
            const float d = __fsub_rn(__fadd_rn(znv[p], ens_np[code]),
                                      __fmul_rn(2.0f, t2f));
            if (d < bestd_s[p] || (d == bestd_s[p] && code < bestk_s[p])) {
                bestd_s[p] = d; bestk_s[p] = code;
            }
        }
        __syncthreads();
    }
    if (t < npts) idxf[pn[t]] = (float)bestk_s[t];
}

// ---------------------------------------------------------------------------
// outputs (verified round 2) — overwrites the scratch regions.
// ---------------------------------------------------------------------------
__global__ __launch_bounds__(256)
void vq_outputs_kernel(const float* __restrict__ z, const float* __restrict__ emb,
                       const float* __restrict__ idxf,
                       float* __restrict__ out_q, float* __restrict__ out_loss)
{
    __shared__ float zts[32 * 257];
    __shared__ int   ids[32];

    const int t  = threadIdx.x;
    const int bh = blockIdx.x;
    const int b  = bh >> 5, h = bh & 31;
    const int n0 = bh * 32;

    if (t < 32) ids[t] = (int)idxf[n0 + t];
    __syncthreads();

    const size_t zbase = (size_t)b * (ZC * 1024) + h * 32;

    for (int rep = 0; rep < 32; ++rep) {
        const int flat = rep * 256 + t;
        const int c = flat >> 5;
        const int ww = flat & 31;
        const size_t ga = zbase + (size_t)c * 1024 + ww;
        const float zv = z[ga];
        zts[ww * 257 + c] = zv;
        out_q[ga] = emb[(size_t)ids[ww] * ZC + c];
    }
    __syncthreads();

    for (int rep = 0; rep < 32; ++rep) {
        const float e = emb[(size_t)ids[rep] * ZC + t];
        const float d = e - zts[rep * 257 + t];
        out_loss[(size_t)(n0 + rep) * ZC + t] = 1.25f * d * d;
    }
}

extern "C" void kernel_launch(void* const* d_in, const int* in_sizes, int n_in,
                              void* d_out, int out_size, void* d_ws, size_t ws_size,
                              hipStream_t stream)
{
    const float* z   = (const float*)d_in[0];   // [32,256,32,32]
    const float* emb = (const float*)d_in[1];   // [1024,256]
    float* out      = (float*)d_out;
    float* out_q    = out;                       // 8388608 floats
    float* out_loss = out + 8388608;             // 8388608 floats
    float* out_idx  = out + 16777216;            // 32768 floats

    // scratch carved from output regions (fully overwritten by final kernels):
    unsigned short* Ab = (unsigned short*)d_out;                       // 16 MiB (out_q)
    unsigned short* Bb = (unsigned short*)((char*)d_out + 33554432);   // 512 KiB
    float* ensg = (float*)((char*)d_out + 34603008);                   // 4 KiB
    int*   cnt  = (int*)  ((char*)d_out + 34607104);                   // 4 B
    int*   list = (int*)  ((char*)d_out + 34607168);                   // 128 KiB
    float* pV1  = (float*)((char*)d_out + 34738240);                   // 256 KiB
    float* pV2  = (float*)((char*)d_out + 35000384);                   // 256 KiB
    int*   pI   = (int*)  ((char*)d_out + 35262528);                   // 256 KiB

    vq_prep_z        <<<4096, 256, 0, stream>>>(z, Ab);
    vq_prep_e        <<<128,  256, 0, stream>>>(emb, Bb);
    vq_ens_np        <<<32,   256, 0, stream>>>(emb, ensg, cnt);
    vq_gemm_argmin   <<<1024, 256, 0, stream>>>(Ab, Bb, ensg, pV1, pV2, pI);
    vq_merge         <<<128,  256, 0, stream>>>(pV1, pV2, pI, out_idx, cnt, list);
    vq_fixup6        <<<8192, 256, 0, stream>>>(z, emb, ensg, out_idx, cnt, list);
    vq_outputs_kernel<<<1024, 256, 0, stream>>>(z, emb, out_idx, out_q, out_loss);
}